// Round 1
// baseline (104.320 us; speedup 1.0000x reference)
//
#include <hip/hip_runtime.h>

#define LN_EPS 1e-5f

static constexpr int Hc    = 512;
static constexpr int Fc    = 16;
static constexpr int NROWS = 128 * 1024;   // B*S

// kernel 1: bsum[h] = sum_i b[i][h]   (512 floats into d_ws)
__global__ void bsum_kernel(const float* __restrict__ b, float* __restrict__ bsum) {
    int h = threadIdx.x;
    float s = 0.f;
#pragma unroll
    for (int i = 0; i < Fc; ++i) s += b[i * Hc + h];
    bsum[h] = s;
}

// kernel 2: one wave per row; each lane owns 8 output columns:
//   h0 = lane*4 .. lane*4+3   and   h1 = h0+256 .. h0+259
__global__ __launch_bounds__(256) void fused_kernel(
    const float* __restrict__ x, const float* __restrict__ W,
    const float* __restrict__ emb, const float* __restrict__ bsum,
    const float* __restrict__ gamma, const float* __restrict__ beta,
    float* __restrict__ out, int nwaves)
{
    const int lane = threadIdx.x & 63;
    const int wid  = blockIdx.x * (blockDim.x >> 6) + (threadIdx.x >> 6);
    const int h0 = lane * 4;
    const int h1 = h0 + 256;

    // register-resident W panel: 16 rows x 8 cols per lane
    float4 w0[Fc], w1[Fc];
#pragma unroll
    for (int i = 0; i < Fc; ++i) {
        w0[i] = *reinterpret_cast<const float4*>(&W[i * Hc + h0]);
        w1[i] = *reinterpret_cast<const float4*>(&W[i * Hc + h1]);
    }
    const float4 bs0 = *reinterpret_cast<const float4*>(&bsum[h0]);
    const float4 bs1 = *reinterpret_cast<const float4*>(&bsum[h1]);
    const float4 g0  = *reinterpret_cast<const float4*>(&gamma[h0]);
    const float4 g1  = *reinterpret_cast<const float4*>(&gamma[h1]);
    const float4 be0 = *reinterpret_cast<const float4*>(&beta[h0]);
    const float4 be1 = *reinterpret_cast<const float4*>(&beta[h1]);

    for (int row = wid; row < NROWS; row += nwaves) {
        const int rowu = __builtin_amdgcn_readfirstlane(row);  // wave-uniform -> scalar loads
        const int s    = rowu & 1023;                          // S == 1024

        // x row: 16 floats, wave-uniform address
        const float* xr = x + (size_t)rowu * Fc;
        float xs[16];
        {
            float4 t0 = *reinterpret_cast<const float4*>(xr + 0);
            float4 t1 = *reinterpret_cast<const float4*>(xr + 4);
            float4 t2 = *reinterpret_cast<const float4*>(xr + 8);
            float4 t3 = *reinterpret_cast<const float4*>(xr + 12);
            xs[0]=t0.x; xs[1]=t0.y; xs[2]=t0.z; xs[3]=t0.w;
            xs[4]=t1.x; xs[5]=t1.y; xs[6]=t1.z; xs[7]=t1.w;
            xs[8]=t2.x; xs[9]=t2.y; xs[10]=t2.z; xs[11]=t2.w;
            xs[12]=t3.x; xs[13]=t3.y; xs[14]=t3.z; xs[15]=t3.w;
        }

        const float* er = emb + (size_t)s * Hc;
        const float4 e0 = *reinterpret_cast<const float4*>(&er[h0]);
        const float4 e1 = *reinterpret_cast<const float4*>(&er[h1]);

        float4 a0, a1;
        a0.x = bs0.x + e0.x; a0.y = bs0.y + e0.y; a0.z = bs0.z + e0.z; a0.w = bs0.w + e0.w;
        a1.x = bs1.x + e1.x; a1.y = bs1.y + e1.y; a1.z = bs1.z + e1.z; a1.w = bs1.w + e1.w;

#pragma unroll
        for (int i = 0; i < Fc; ++i) {
            a0.x = fmaf(xs[i], w0[i].x, a0.x);
            a0.y = fmaf(xs[i], w0[i].y, a0.y);
            a0.z = fmaf(xs[i], w0[i].z, a0.z);
            a0.w = fmaf(xs[i], w0[i].w, a0.w);
            a1.x = fmaf(xs[i], w1[i].x, a1.x);
            a1.y = fmaf(xs[i], w1[i].y, a1.y);
            a1.z = fmaf(xs[i], w1[i].z, a1.z);
            a1.w = fmaf(xs[i], w1[i].w, a1.w);
        }

        // LayerNorm over H=512: per-lane partials then 64-lane butterfly
        float sum = a0.x + a0.y + a0.z + a0.w + a1.x + a1.y + a1.z + a1.w;
        float ssq = a0.x*a0.x + a0.y*a0.y + a0.z*a0.z + a0.w*a0.w
                  + a1.x*a1.x + a1.y*a1.y + a1.z*a1.z + a1.w*a1.w;
#pragma unroll
        for (int m = 32; m > 0; m >>= 1) {
            sum += __shfl_xor(sum, m, 64);
            ssq += __shfl_xor(ssq, m, 64);
        }
        const float mean = sum * (1.0f / 512.0f);
        const float var  = ssq * (1.0f / 512.0f) - mean * mean;
        const float rs   = rsqrtf(var + LN_EPS);

        float4 r0, r1;
        r0.x = (a0.x - mean) * rs * g0.x + be0.x;
        r0.y = (a0.y - mean) * rs * g0.y + be0.y;
        r0.z = (a0.z - mean) * rs * g0.z + be0.z;
        r0.w = (a0.w - mean) * rs * g0.w + be0.w;
        r1.x = (a1.x - mean) * rs * g1.x + be1.x;
        r1.y = (a1.y - mean) * rs * g1.y + be1.y;
        r1.z = (a1.z - mean) * rs * g1.z + be1.z;
        r1.w = (a1.w - mean) * rs * g1.w + be1.w;

        float* orow = out + (size_t)rowu * Hc;
        *reinterpret_cast<float4*>(&orow[h0]) = r0;
        *reinterpret_cast<float4*>(&orow[h1]) = r1;
    }
}

extern "C" void kernel_launch(void* const* d_in, const int* in_sizes, int n_in,
                              void* d_out, int out_size, void* d_ws, size_t ws_size,
                              hipStream_t stream) {
    const float* x     = (const float*)d_in[0];
    const float* W     = (const float*)d_in[1];
    const float* b     = (const float*)d_in[2];
    const float* emb   = (const float*)d_in[3];
    const float* gamma = (const float*)d_in[4];
    const float* beta  = (const float*)d_in[5];
    float* out  = (float*)d_out;
    float* bsum = (float*)d_ws;

    bsum_kernel<<<1, Hc, 0, stream>>>(b, bsum);

    const int blocks = 1024;           // 4096 waves, 32 rows each
    const int nwaves = blocks * 4;
    fused_kernel<<<blocks, 256, 0, stream>>>(x, W, emb, bsum, gamma, beta, out, nwaves);
}

// Round 2
// 102.473 us; speedup vs baseline: 1.0180x; 1.0180x over previous
//
#include <hip/hip_runtime.h>

#define LN_EPS 1e-5f

static constexpr int Hc    = 512;
static constexpr int Fc    = 16;
static constexpr int Sc    = 1024;
static constexpr int NROWS = 128 * 1024;  // B*S
static constexpr int RPB   = 64;          // rows per block
static constexpr int NIT   = RPB / 2;     // 2 rows in flight per iteration (one per wave-pair)

// kernel 1: bsum[h] = sum_i b[i][h]
__global__ void bsum_kernel(const float* __restrict__ b, float* __restrict__ bsum) {
    int h = blockIdx.x * 64 + threadIdx.x;
    float s = 0.f;
#pragma unroll
    for (int i = 0; i < Fc; ++i) s += b[i * Hc + h];
    bsum[h] = s;
}

// kernel 2: 4 waves/block; waves (0,1) own row A, waves (2,3) own row B.
// Each wave covers 256 columns (4 cols/lane) -> W panel is 64 VGPRs.
// LN stats: 6-step intra-wave butterfly, then a 2-float LDS exchange between
// paired waves using raw s_barrier + lgkmcnt(0) (keeps prefetch loads in flight).
__global__ __launch_bounds__(256) void fused_kernel(
    const float* __restrict__ x, const float* __restrict__ W,
    const float* __restrict__ emb, const float* __restrict__ bsum,
    const float* __restrict__ gamma, const float* __restrict__ beta,
    float* __restrict__ out)
{
    __shared__ float2 part[2][4];   // [parity][wave]

    const int lane = threadIdx.x & 63;
    const int wv   = threadIdx.x >> 6;   // 0..3
    const int half = wv & 1;             // which 256-col half
    const int rsel = wv >> 1;            // which row of the pair
    const int h    = half * 256 + lane * 4;
    const int base = blockIdx.x * RPB;

    // register-resident W panel: 16 rows x 4 cols per lane
    float4 Wp[Fc];
#pragma unroll
    for (int i = 0; i < Fc; ++i)
        Wp[i] = *reinterpret_cast<const float4*>(&W[i * Hc + h]);
    const float4 bs = *reinterpret_cast<const float4*>(&bsum[h]);
    const float4 g  = *reinterpret_cast<const float4*>(&gamma[h]);
    const float4 be = *reinterpret_cast<const float4*>(&beta[h]);

    float4 xA[4], xB[4], eA, eB;

    auto LOAD = [&](float4* xs, float4& e, int it) {
        const int itc = (it < NIT) ? it : (NIT - 1);             // clamp tail prefetch
        const int row = __builtin_amdgcn_readfirstlane(base + itc * 2 + rsel);
        const float* xr = x + (size_t)row * Fc;
        xs[0] = *reinterpret_cast<const float4*>(xr + 0);
        xs[1] = *reinterpret_cast<const float4*>(xr + 4);
        xs[2] = *reinterpret_cast<const float4*>(xr + 8);
        xs[3] = *reinterpret_cast<const float4*>(xr + 12);
        e = *reinterpret_cast<const float4*>(&emb[(size_t)(row & (Sc - 1)) * Hc + h]);
    };

    auto COMPUTE = [&](const float4* xs, const float4& e, int it, int parity) {
        const int row = __builtin_amdgcn_readfirstlane(base + it * 2 + rsel);

        float4 a;
        a.x = bs.x + e.x; a.y = bs.y + e.y; a.z = bs.z + e.z; a.w = bs.w + e.w;
        const float* xf = reinterpret_cast<const float*>(xs);
#pragma unroll
        for (int i = 0; i < Fc; ++i) {
            const float xi = xf[i];
            a.x = fmaf(xi, Wp[i].x, a.x);
            a.y = fmaf(xi, Wp[i].y, a.y);
            a.z = fmaf(xi, Wp[i].z, a.z);
            a.w = fmaf(xi, Wp[i].w, a.w);
        }

        float sum = a.x + a.y + a.z + a.w;
        float ssq = fmaf(a.x, a.x, fmaf(a.y, a.y, fmaf(a.z, a.z, a.w * a.w)));
#pragma unroll
        for (int m = 32; m > 0; m >>= 1) {
            sum += __shfl_xor(sum, m, 64);
            ssq += __shfl_xor(ssq, m, 64);
        }

        // exchange half-row stats with the paired wave (wv^1)
        if (lane == 0) part[parity][wv] = make_float2(sum, ssq);
        asm volatile("s_waitcnt lgkmcnt(0)" ::: "memory");  // LDS write visible; vmcnt untouched
        __builtin_amdgcn_s_barrier();
        asm volatile("" ::: "memory");
        const float2 p = part[parity][wv ^ 1];
        sum += p.x; ssq += p.y;

        const float mean = sum * (1.0f / 512.0f);
        const float var  = ssq * (1.0f / 512.0f) - mean * mean;
        const float rs   = rsqrtf(var + LN_EPS);

        float4 r;
        r.x = (a.x - mean) * rs * g.x + be.x;
        r.y = (a.y - mean) * rs * g.y + be.y;
        r.z = (a.z - mean) * rs * g.z + be.z;
        r.w = (a.w - mean) * rs * g.w + be.w;
        *reinterpret_cast<float4*>(&out[(size_t)row * Hc + h]) = r;
    };

    // software pipeline: prefetch one row-pair ahead, register ping-pong
    LOAD(xA, eA, 0);
    for (int it = 0; it < NIT; it += 2) {
        LOAD(xB, eB, it + 1);
        COMPUTE(xA, eA, it, 0);
        LOAD(xA, eA, it + 2);
        COMPUTE(xB, eB, it + 1, 1);
    }
}

extern "C" void kernel_launch(void* const* d_in, const int* in_sizes, int n_in,
                              void* d_out, int out_size, void* d_ws, size_t ws_size,
                              hipStream_t stream) {
    const float* x     = (const float*)d_in[0];
    const float* W     = (const float*)d_in[1];
    const float* b     = (const float*)d_in[2];
    const float* emb   = (const float*)d_in[3];
    const float* gamma = (const float*)d_in[4];
    const float* beta  = (const float*)d_in[5];
    float* out  = (float*)d_out;
    float* bsum = (float*)d_ws;

    bsum_kernel<<<8, 64, 0, stream>>>(b, bsum);

    const int blocks = NROWS / RPB;   // 2048
    fused_kernel<<<blocks, 256, 0, stream>>>(x, W, emb, bsum, gamma, beta, out);
}